// Round 4
// baseline (232.834 us; speedup 1.0000x reference)
//
#include <hip/hip_runtime.h>

#define NFFT 1024

// ---------- complex helpers ----------
__device__ __forceinline__ float2 cmul(float2 a, float2 b) {
  return make_float2(fmaf(a.x, b.x, -a.y * b.y), fmaf(a.x, b.y, a.y * b.x));
}
__device__ __forceinline__ float2 cadd(float2 a, float2 b) { return make_float2(a.x + b.x, a.y + b.y); }
__device__ __forceinline__ float2 csub(float2 a, float2 b) { return make_float2(a.x - b.x, a.y - b.y); }

// y_k = sum_r v_r * e^{-2*pi*i*k*r/4}
__device__ __forceinline__ void dft4(const float2 v[4], float2 y[4]) {
  float2 s02 = cadd(v[0], v[2]), d02 = csub(v[0], v[2]);
  float2 s13 = cadd(v[1], v[3]), d13 = csub(v[1], v[3]);
  y[0] = cadd(s02, s13);
  y[2] = csub(s02, s13);
  y[1] = make_float2(d02.x + d13.y, d02.y - d13.x);  // d02 + (-i)*d13
  y[3] = make_float2(d02.x - d13.y, d02.y + d13.x);  // d02 + (+i)*d13
}

// Wave-autonomous 1024-pt forward FFT: N = 64 (cross-lane, shuffle DIF) x 16
// (in-lane). No LDS, no barriers. Lane p loads the 16-complex chunk at
// 16*bitrev6(p) (logical index l = bitrev6(p)); after the 6 DIF stages the
// lane naturally holds output frequency k2 = p (bitrev of bitrev), so stores
// are coalesced and naturally ordered. Verified by hand on the 4-lane analog.
__global__ __launch_bounds__(256, 6) void fft1024_kernel(const float* __restrict__ in,
                                                         float* __restrict__ out) {
  const int l = threadIdx.x & 63;
  const int wave = threadIdx.x >> 6;
  const int row = blockIdx.x * 4 + wave;

  // bitrev6: bit0<->bit5, bit1<->bit4, bit2<->bit3
  const int rb = ((l & 1) << 5) | ((l & 2) << 3) | ((l & 4) << 1) |
                 ((l & 8) >> 1) | ((l & 16) >> 3) | ((l & 32) >> 5);

  float2 v[16];

  // ---- load: v[r] = x[16*rb + r], as 8 dwordx4
  {
    const float4* in4 = reinterpret_cast<const float4*>(in) + (size_t)row * 512;
    float4* vf4 = reinterpret_cast<float4*>(v);
    #pragma unroll
    for (int o = 0; o < 8; ++o) vf4[o] = in4[8 * rb + o];
  }

  // ---- cross-lane DFT-64 over logical l (DIF radix-2, 6 shuffle stages)
  // stage s: physical mask 1<<s == logical distance 32>>s.
  // twiddle t_s = exp(-i*pi*(rb mod d)/d), d = 32>>s; derived by squaring:
  // t_{s+1} = t_s^2 * (-1)^{bit (4-s) of rb}.  Last stage (s=5) twiddle = 1.
  {
    float sn, cs;
    __sincosf(-3.14159265358979323f * (float)(rb & 31) / 32.0f, &sn, &cs);
    float2 T = make_float2(cs, sn);
    #pragma unroll
    for (int s = 0; s < 6; ++s) {
      const int mask = 1 << s;
      const bool up = (l & mask) != 0;
      const float sgn = up ? -1.0f : 1.0f;
      const float2 tt = up ? T : make_float2(1.0f, 0.0f);
      #pragma unroll
      for (int r = 0; r < 16; ++r) {
        float px = __shfl_xor(v[r].x, mask, 64);
        float py = __shfl_xor(v[r].y, mask, 64);
        float ax = fmaf(sgn, v[r].x, px);   // lower: V+P ; upper: P-V
        float ay = fmaf(sgn, v[r].y, py);
        if (s < 5) v[r] = cmul(make_float2(ax, ay), tt);
        else       v[r] = make_float2(ax, ay);
      }
      if (s < 4) {
        float2 T2 = cmul(T, T);
        const float fb = ((rb >> (4 - s)) & 1) ? -1.0f : 1.0f;
        T = make_float2(T2.x * fb, T2.y * fb);
      }
    }
  }

  // ---- twiddle: v[r] *= exp(-2*pi*i * r * k2 / 1024), k2 = l
  {
    float sn, cs;
    __sincosf(-6.283185307179586f * (float)l / 1024.0f, &sn, &cs);
    const float2 u = make_float2(cs, sn);
    float2 t = u;
    #pragma unroll
    for (int r = 1; r < 16; ++r) {
      v[r] = cmul(v[r], t);
      if (r < 15) t = cmul(t, u);
    }
  }

  // ---- in-lane DFT-16 over r (natural in / natural out), then store
  // Step A: n = n2 + 4*n1; DFT4 over n1 -> slot n2 + 4*k1
  #pragma unroll
  for (int n2 = 0; n2 < 4; ++n2) {
    float2 a[4] = {v[n2], v[n2 + 4], v[n2 + 8], v[n2 + 12]};
    float2 y[4];
    dft4(a, y);
    v[n2] = y[0]; v[n2 + 4] = y[1]; v[n2 + 8] = y[2]; v[n2 + 12] = y[3];
  }
  // Step B: twiddle W16^{n2*k1} at slot n2 + 4*k1
  {
    const float C1 = 0.9238795325112867f;   // cos(pi/8)
    const float S1 = 0.3826834323650898f;   // sin(pi/8)
    const float R2 = 0.7071067811865476f;   // sqrt(2)/2
    v[1 + 4]  = cmul(v[1 + 4],  make_float2(C1, -S1));    // W^1
    v[1 + 8]  = cmul(v[1 + 8],  make_float2(R2, -R2));    // W^2
    v[1 + 12] = cmul(v[1 + 12], make_float2(S1, -C1));    // W^3
    v[2 + 4]  = cmul(v[2 + 4],  make_float2(R2, -R2));    // W^2
    v[2 + 8]  = make_float2(v[2 + 8].y, -v[2 + 8].x);     // W^4 = -i
    v[2 + 12] = cmul(v[2 + 12], make_float2(-R2, -R2));   // W^6
    v[3 + 4]  = cmul(v[3 + 4],  make_float2(S1, -C1));    // W^3
    v[3 + 8]  = cmul(v[3 + 8],  make_float2(-R2, -R2));   // W^6
    v[3 + 12] = cmul(v[3 + 12], make_float2(-C1, S1));    // W^9
  }
  // Step C: DFT4 over n2 -> X[k1 + 4*k2]; store X[l + 64*k] coalesced
  {
    float2* out2 = reinterpret_cast<float2*>(out) + (size_t)row * NFFT;
    #pragma unroll
    for (int k1 = 0; k1 < 4; ++k1) {
      float2 a[4] = {v[4 * k1], v[4 * k1 + 1], v[4 * k1 + 2], v[4 * k1 + 3]};
      float2 y[4];
      dft4(a, y);
      #pragma unroll
      for (int k2 = 0; k2 < 4; ++k2) {
        out2[l + 64 * (k1 + 4 * k2)] = y[k2];
      }
    }
  }
}

extern "C" void kernel_launch(void* const* d_in, const int* in_sizes, int n_in,
                              void* d_out, int out_size, void* d_ws, size_t ws_size,
                              hipStream_t stream) {
  const float* x = (const float*)d_in[0];
  float* out = (float*)d_out;
  const int rows = in_sizes[0] / (2 * NFFT);   // 16384 rows of 1024 complex
  fft1024_kernel<<<rows / 4, 256, 0, stream>>>(x, out);
}